// Round 12
// baseline (112.782 us; speedup 1.0000x reference)
//
#include <hip/hip_runtime.h>

#define NN 32
#define DSA 64
#define DH 128
#define THREADS 512

typedef float f32x4 __attribute__((ext_vector_type(4)));
typedef float f32x16 __attribute__((ext_vector_type(16)));
typedef short short8 __attribute__((ext_vector_type(8)));
typedef __bf16 bfrag __attribute__((ext_vector_type(8)));
typedef unsigned short us4 __attribute__((ext_vector_type(4)));

#define MFMA32(a, b, c) __builtin_amdgcn_mfma_f32_32x32x16_bf16((a), (b), (c), 0, 0, 0)

// swizzled f32 index for P/Q [32][128]: XOR row bits into col bits 2-4 (f32x4-safe)
__device__ __forceinline__ int idxf(int r, int col) { return r * DH + (col ^ ((r & 7) << 2)); }
// swizzled ushort index, mask M on row: XOR into k bits 3+ (bfrag/us4-safe)
__device__ __forceinline__ int idxu(int r, int k, int rs, int mask) {
  return r * rs + (k ^ ((r & mask) << 3));
}

// f32 -> (hi = truncated bf16, lo = RNE bf16 of residual); a ≈ hi+lo to ~2^-17 rel.
__device__ __forceinline__ void split2(float f, unsigned short& h, unsigned short& l) {
  unsigned u = __float_as_uint(f);
  h = (unsigned short)(u >> 16);
  float lo = f - __uint_as_float(u & 0xffff0000u);
  unsigned v = __float_as_uint(lo);
  l = (unsigned short)((v + 0x7fffu + ((v >> 16) & 1u)) >> 16);
}

// 8 f32 (two float4) -> hi/lo bf16 fragments
__device__ __forceinline__ void cvt8(const float4 a, const float4 b, bfrag& bh, bfrag& bl) {
  float f[8] = {a.x, a.y, a.z, a.w, b.x, b.y, b.z, b.w};
  short8 h, l;
  #pragma unroll
  for (int j = 0; j < 8; ++j) {
    unsigned short hh, ll;
    split2(f[j], hh, ll);
    h[j] = (short)hh;
    l[j] = (short)ll;
  }
  bh = __builtin_bit_cast(bfrag, h);
  bl = __builtin_bit_cast(bfrag, l);
}

// B fragment: W row `roww`, cols [o, o+8). PRE: pre-split planes; else inline cvt.
template<bool PRE>
__device__ __forceinline__ void fetch_b(const float* __restrict__ W, int ld, int roww, int o,
                                        const unsigned short* __restrict__ Bh,
                                        const unsigned short* __restrict__ Bl,
                                        bfrag& bh, bfrag& bl) {
  if constexpr (PRE) {
    bh = *(const bfrag*)(Bh + roww * ld + o);
    bl = *(const bfrag*)(Bl + roww * ld + o);
  } else {
    const float* wp = W + roww * ld + o;
    cvt8(*(const float4*)wp, *(const float4*)(wp + 4), bh, bl);
  }
}

// One 32x32 GEMM part over NKT k16-tiles: acc += A(32 x 16*NKT) . W[32cb+n, c0:...]^T.
// A layout: row = lane&31, k = kt*16 + 8*(lane>>5) + j.  B: col = lane&31, same k.
template<int NKT, int RS, int MASK, bool PRE>
__device__ __forceinline__ void part32(const unsigned short* __restrict__ Ah,
                                       const unsigned short* __restrict__ Al,
                                       const float* __restrict__ W, int ld, int c0,
                                       const unsigned short* __restrict__ Bh,
                                       const unsigned short* __restrict__ Bl,
                                       int lane, int colblk, f32x16& acc) {
  const int n = lane & 31, h2 = lane >> 5;
  const int rw = colblk * 32 + n;
  static_assert(NKT % 4 == 0, "");
  #pragma unroll
  for (int base = 0; base < NKT; base += 4) {
    bfrag bh[4], bl[4];
    #pragma unroll
    for (int q = 0; q < 4; ++q)
      fetch_b<PRE>(W, ld, rw, c0 + (base + q) * 16 + h2 * 8, Bh, Bl, bh[q], bl[q]);
    #pragma unroll
    for (int q = 0; q < 4; ++q) {
      const int ko = (base + q) * 16 + h2 * 8;
      const int ia = idxu(n, ko, RS, MASK);
      bfrag a_h = *(const bfrag*)(Ah + ia);
      bfrag a_l = *(const bfrag*)(Al + ia);
      acc = MFMA32(a_h, bh[q], acc);
      acc = MFMA32(a_h, bl[q], acc);
      acc = MFMA32(a_l, bh[q], acc);
      acc = MFMA32(a_l, bl[q], acc);
    }
  }
}

// C/D layout (m74/m101): col = lane&31, row = (reg&3) + 8*(reg>>2) + 4*(lane>>5)
template<bool BIAS>
__device__ __forceinline__ void store32(float* __restrict__ Bf, const f32x16& acc,
                                        int lane, int colblk, float bcol) {
  const int n = lane & 31, h2 = lane >> 5;
  const int col = colblk * 32 + n;
  #pragma unroll
  for (int r = 0; r < 16; ++r) {
    const int row = (r & 3) + 8 * (r >> 2) + 4 * h2;
    Bf[idxf(row, col)] = acc[r] + (BIAS ? bcol : 0.f);
  }
}

// wb merge: v = relu(acc + Pf_partial + bias) -> swizzled split-bf16 U (mask 15)
__device__ __forceinline__ void merge_store_v(const float* __restrict__ Pf,
                                              unsigned short* __restrict__ Uh,
                                              unsigned short* __restrict__ Ul,
                                              const f32x16& acc, int lane, int colblk,
                                              float bcol) {
  const int n = lane & 31, h2 = lane >> 5;
  const int col = colblk * 32 + n;
  #pragma unroll
  for (int r = 0; r < 16; ++r) {
    const int row = (r & 3) + 8 * (r >> 2) + 4 * h2;
    const float v = fmaxf(acc[r] + Pf[idxf(row, col)] + bcol, 0.f);
    unsigned short hh, ll;
    split2(v, hh, ll);
    const int u = idxu(row, col, DH, 15);
    Uh[u] = hh;
    Ul[u] = ll;
  }
}

// U[i][h] = sum_{j!=i} relu(P[j][h] + Q[i][h]) -> split-bf16 (bias pre-folded into Q).
// lane = (j-half, col-quad, i-group): 16 distinct P reads/lane + pair-combine via shfl.
__device__ __forceinline__ void aggregate32(const float* __restrict__ Pf,
                                            const float* __restrict__ Qf,
                                            unsigned short* __restrict__ Uh,
                                            unsigned short* __restrict__ Ul, int t) {
  const int w = t >> 6, lane = t & 63;
  const int jh = lane & 1;               // j in [16*jh, 16*jh+16)
  const int cq = (lane >> 1) & 3;        // col quad within wave's 16 cols
  const int ig = lane >> 3;              // i group: rows 4*ig .. 4*ig+3
  const int col4 = 16 * w + 4 * cq;
  const int i0 = 4 * ig;
  f32x4 cv[4], sg[4];
  #pragma unroll
  for (int m = 0; m < 4; ++m) {
    cv[m] = *(const f32x4*)(Qf + idxf(i0 + m, col4));
    sg[m] = (f32x4){0.f, 0.f, 0.f, 0.f};
  }
  #pragma unroll 4
  for (int jj = 0; jj < 16; ++jj) {
    f32x4 av = *(const f32x4*)(Pf + idxf(16 * jh + jj, col4));
    #pragma unroll
    for (int m = 0; m < 4; ++m)
      #pragma unroll
      for (int e = 0; e < 4; ++e)
        sg[m][e] += fmaxf(av[e] + cv[m][e], 0.f);
  }
  #pragma unroll
  for (int m = 0; m < 4; ++m)
    #pragma unroll
    for (int e = 0; e < 4; ++e)
      sg[m][e] += __shfl_xor(sg[m][e], 1);     // combine j-halves across the lane pair
  #pragma unroll
  for (int mm = 0; mm < 2; ++mm) {             // even lane writes m 0-1, odd m 2-3
    const int m = 2 * jh + mm;
    const int i = i0 + m;
    f32x4 av = *(const f32x4*)(Pf + idxf(i, col4));
    us4 hh, ll;
    #pragma unroll
    for (int e = 0; e < 4; ++e) {
      const float self = fmaxf(av[e] + cv[m][e], 0.f);
      const float val = sg[m][e] - self;
      unsigned short a_, b_;
      split2(val, a_, b_);
      hh[e] = a_;
      ll[e] = b_;
    }
    const int u = idxu(i, col4, DH, 15);
    *(us4*)(Uh + u) = hh;
    *(us4*)(Ul + u) = ll;
  }
}

// Pre-split all weights f32 -> (hi, lo) bf16 planes in d_ws. 24576 float4 total.
__global__ void preconv(const float* __restrict__ Wm1, const float* __restrict__ Wu1,
                        const float* __restrict__ Wm2, const float* __restrict__ Wu2,
                        unsigned short* __restrict__ ws) {
  const int tid = blockIdx.x * blockDim.x + threadIdx.x;
  const float* src; unsigned short *dh, *dl; int loc;
  if (tid < 4096)        { src = Wm1; dh = ws;          dl = ws + 16384;  loc = tid; }
  else if (tid < 10240)  { src = Wu1; dh = ws + 32768;  dl = ws + 57344;  loc = tid - 4096; }
  else if (tid < 18432)  { src = Wm2; dh = ws + 81920;  dl = ws + 114688; loc = tid - 10240; }
  else                   { src = Wu2; dh = ws + 147456; dl = ws + 172032; loc = tid - 18432; }
  float4 v = *(const float4*)(src + loc * 4);
  float f[4] = {v.x, v.y, v.z, v.w};
  us4 h, l;
  #pragma unroll
  for (int j = 0; j < 4; ++j) {
    unsigned short hh, ll;
    split2(f[j], hh, ll);
    h[j] = hh;
    l[j] = ll;
  }
  *(us4*)(dh + loc * 4) = h;
  *(us4*)(dl + loc * 4) = l;
}

// LDS: X (4K+4K) + Pf 16K + Qf 16K + U (8K+8K) + red = 56 KB -> 2 blocks/CU,
// 8 waves/block, 16 waves/CU. Waves 0-3 (wa) and 4-7 (wb) pair on col-block w&3.
template<bool PRE>
__global__ __launch_bounds__(THREADS, 4)
void mgn_mfma(const float* __restrict__ x,
              const float* __restrict__ Wm1, const float* __restrict__ bm1,
              const float* __restrict__ Wm2, const float* __restrict__ bm2,
              const float* __restrict__ Wu1, const float* __restrict__ bu1,
              const float* __restrict__ Wu2, const float* __restrict__ bu2,
              const float* __restrict__ Wv,  const float* __restrict__ bv,
              const unsigned short* __restrict__ wsplit,
              float* __restrict__ out) {
  __shared__ __align__(16) unsigned short Xh[NN * DSA], Xl[NN * DSA];
  __shared__ __align__(16) float Pf[NN * DH];
  __shared__ __align__(16) float Qf[NN * DH];
  __shared__ __align__(16) unsigned short Uh[NN * DH], Ul[NN * DH];
  __shared__ float red[4];

  const int t = threadIdx.x;
  const int b = blockIdx.x;
  const int w = t >> 6;
  const int lane = t & 63;
  const int n = lane & 31;
  const bool wa = (w < 4);
  const int cb = w & 3;              // col-block: cols [32cb, 32cb+32)

  // pre-split W plane pointers (PRE path)
  const unsigned short *m1h = wsplit,           *m1l = wsplit + 16384;
  const unsigned short *u1h = wsplit + 32768,   *u1l = wsplit + 57344;
  const unsigned short *m2h = wsplit + 81920,   *m2l = wsplit + 114688;
  const unsigned short *u2h = wsplit + 147456,  *u2l = wsplit + 172032;

  // per-lane bias / Wv for col = 32cb + n
  const int col = 32 * cb + n;
  const float bm1c = bm1[col], bu1c = bu1[col];
  const float bm2c = bm2[col], bu2c = bu2[col];
  const float wvc = Wv[col];

  // ---- stage x_b as swizzled split-bf16 (one f32x4 per thread) ----
  {
    const float* xb = x + b * (NN * DSA);
    const int row = t >> 4;
    const int c0 = (t & 15) << 2;
    float4 v = *(const float4*)(xb + (t << 2));
    float fv[4] = {v.x, v.y, v.z, v.w};
    us4 hh, ll;
    #pragma unroll
    for (int j = 0; j < 4; ++j) {
      unsigned short a_, b_;
      split2(fv[j], a_, b_);
      hh[j] = a_;
      ll[j] = b_;
    }
    const int idx = idxu(row, c0, DSA, 7);
    *(us4*)(Xh + idx) = hh;
    *(us4*)(Xl + idx) = ll;
  }
  __syncthreads();                                   // B1: X staged

  f32x16 acc;

  // ---- phase 1: wa: A1 = x@Wm1L^T -> Pf ; wb: C1 = x@Wm1R^T + bm1 -> Qf ----
  acc = (f32x16)(0.f);
  if (wa) {
    part32<4, DSA, 7, PRE>(Xh, Xl, Wm1, 2 * DSA, 0, m1h, m1l, lane, cb, acc);
    store32<false>(Pf, acc, lane, cb, 0.f);
  } else {
    part32<4, DSA, 7, PRE>(Xh, Xl, Wm1, 2 * DSA, DSA, m1h, m1l, lane, cb, acc);
    store32<true>(Qf, acc, lane, cb, bm1c);
  }
  __syncthreads();                                   // B2: P,Q complete

  // ---- agg1(P,Q) -> U = R1 (all waves) ----
  aggregate32(Pf, Qf, Uh, Ul, t);
  __syncthreads();                                   // B3: R1 complete

  // ---- phase 2: wa: v1x = x@Wu1x^T -> Pf(partial) ; wb: v1g = R1@Wu1g^T (regs) ----
  acc = (f32x16)(0.f);
  if (wa) {
    part32<4, DSA, 7, PRE>(Xh, Xl, Wu1, DH + DSA, 0, u1h, u1l, lane, cb, acc);
    store32<false>(Pf, acc, lane, cb, 0.f);
  } else {
    part32<8, DH, 15, PRE>(Uh, Ul, Wu1, DH + DSA, DSA, u1h, u1l, lane, cb, acc);
  }
  __syncthreads();                                   // B4: partials in Pf, U reads done
  if (!wa) merge_store_v(Pf, Uh, Ul, acc, lane, cb, bu1c);   // U = V
  __syncthreads();                                   // B5: V complete

  // ---- phase 3: wa: A2 = v1@Wm2L^T -> Pf ; wb: C2 = v1@Wm2R^T + bm2 -> Qf ----
  acc = (f32x16)(0.f);
  if (wa) {
    part32<8, DH, 15, PRE>(Uh, Ul, Wm2, 2 * DH, 0, m2h, m2l, lane, cb, acc);
    store32<false>(Pf, acc, lane, cb, 0.f);
  } else {
    part32<8, DH, 15, PRE>(Uh, Ul, Wm2, 2 * DH, DH, m2h, m2l, lane, cb, acc);
    store32<true>(Qf, acc, lane, cb, bm2c);
  }
  __syncthreads();                                   // B6: P,Q complete; V reads done

  // ---- agg2(P,Q) -> U = R2 (all waves) ----
  aggregate32(Pf, Qf, Uh, Ul, t);
  __syncthreads();                                   // B7: R2 complete

  // ---- phase 4: wa: v2x = x@Wu2x^T -> Pf(partial) ; wb: v2g = R2@Wu2g^T (regs) ----
  acc = (f32x16)(0.f);
  if (wa) {
    part32<4, DSA, 7, PRE>(Xh, Xl, Wu2, DH + DSA, 0, u2h, u2l, lane, cb, acc);
    store32<false>(Pf, acc, lane, cb, 0.f);
  } else {
    part32<8, DH, 15, PRE>(Uh, Ul, Wu2, DH + DSA, DSA, u2h, u2l, lane, cb, acc);
  }
  __syncthreads();                                   // B8: partials in Pf

  // ---- wb: v2 = relu-max -> out partials ----
  if (!wa) {
    const int h2 = lane >> 5;
    float cm = 0.f;                                  // relu >= 0 so init 0 exact
    #pragma unroll
    for (int r = 0; r < 16; ++r) {
      const int row = (r & 3) + 8 * (r >> 2) + 4 * h2;
      cm = fmaxf(cm, acc[r] + Pf[idxf(row, col)] + bu2c);
    }
    cm = fmaxf(cm, __shfl_xor(cm, 32));              // full 32-row max per col
    float part_ = (lane < 32) ? cm * wvc : 0.f;      // count each column once
    #pragma unroll
    for (int off = 16; off >= 1; off >>= 1) part_ += __shfl_xor(part_, off);
    if (lane == 0) red[w - 4] = part_;
  }
  __syncthreads();                                   // B9
  if (t == 0) out[b] = red[0] + red[1] + red[2] + red[3] + bv[0];
}

extern "C" void kernel_launch(void* const* d_in, const int* in_sizes, int n_in,
                              void* d_out, int out_size, void* d_ws, size_t ws_size,
                              hipStream_t stream) {
  (void)n_in; (void)out_size;
  const float* x   = (const float*)d_in[0];
  // d_in[1] = ext_adj: all-pairs-minus-self structure, folded analytically.
  const float* Wm1 = (const float*)d_in[2];
  const float* bm1 = (const float*)d_in[3];
  const float* Wm2 = (const float*)d_in[4];
  const float* bm2 = (const float*)d_in[5];
  const float* Wu1 = (const float*)d_in[6];
  const float* bu1 = (const float*)d_in[7];
  const float* Wu2 = (const float*)d_in[8];
  const float* bu2 = (const float*)d_in[9];
  const float* Wv  = (const float*)d_in[10];
  const float* bv  = (const float*)d_in[11];
  float* out = (float*)d_out;

  const int B = in_sizes[0] / (NN * DSA);   // 512
  const bool pre = ws_size >= 196608u * sizeof(unsigned short);
  if (pre) {
    unsigned short* ws = (unsigned short*)d_ws;
    preconv<<<dim3(96), dim3(256), 0, stream>>>(Wm1, Wu1, Wm2, Wu2, ws);
    mgn_mfma<true><<<dim3(B), dim3(THREADS), 0, stream>>>(
        x, Wm1, bm1, Wm2, bm2, Wu1, bu1, Wu2, bu2, Wv, bv, ws, out);
  } else {
    mgn_mfma<false><<<dim3(B), dim3(THREADS), 0, stream>>>(
        x, Wm1, bm1, Wm2, bm2, Wu1, bu1, Wu2, bu2, Wv, bv, nullptr, out);
  }
}